// Round 5
// baseline (48.380 us; speedup 1.0000x reference)
//
#include <hip/hip_runtime.h>

typedef __bf16 bf16x8 __attribute__((ext_vector_type(8)));
typedef float  f32x16 __attribute__((ext_vector_type(16)));

#define NI 256
#define NT 256
#define NL 32
#define NE 128
#define HW 49
#define NEG_INF (-3.0e38f)
#define CH 16            // texts per chunk (per block)

// ws layout (bf16):
//  wsA: frag gw = (i*2+mh)*8+ks, elem (gw*64+lane)*8+j
//       = img[i, e=ks*16+(lane>>5)*8+j, hw=min(mh*32+(lane&31),48)]   (4 MB)
//  wsB: frag gw = t*8+ks, elem (gw*64+lane)*8+j
//       = txt[t, l=lane&31, e=ks*16+(lane>>5)*8+j]                    (2 MB)

// ---------- pre-kernel: fp32 -> bf16 MFMA-fragment layout ----------
__global__ __launch_bounds__(256, 4)
void prep_kernel(const float* __restrict__ img,
                 const float* __restrict__ txt,
                 __bf16* __restrict__ wsA,
                 __bf16* __restrict__ wsB)
{
    const int tid  = threadIdx.x;
    const int wave = tid >> 6, lane = tid & 63;
    const int ml   = lane & 31, h = lane >> 5;
    const int bid  = blockIdx.x;
    if (bid < 1024) {                       // A-part: 4096 waves
        int gw = bid * 4 + wave;            // (i, mh, ks)
        int i  = gw >> 4, mh = (gw >> 3) & 1, ks = gw & 7;
        int m  = mh * 32 + ml; if (m > HW - 1) m = HW - 1;
        int e0 = ks * 16 + h * 8;
        const float* p = img + ((size_t)i * NE + e0) * HW + m;
        union { __bf16 b[8]; int4 v; } u;
        #pragma unroll
        for (int j = 0; j < 8; ++j) u.b[j] = (__bf16)p[j * HW];
        *(int4*)(wsA + ((size_t)gw * 64 + lane) * 8) = u.v;
    } else {                                // B-part: 2048 waves
        int gw = (bid - 1024) * 4 + wave;   // (t, ks)
        int t  = gw >> 3, ks = gw & 7;
        int e0 = ks * 16 + h * 8;
        const float* p = txt + ((size_t)t * NL + ml) * NE + e0;
        float4 f0 = *(const float4*)p;
        float4 f1 = *(const float4*)(p + 4);
        union { __bf16 b[8]; int4 v; } u;
        u.b[0] = (__bf16)f0.x; u.b[1] = (__bf16)f0.y;
        u.b[2] = (__bf16)f0.z; u.b[3] = (__bf16)f0.w;
        u.b[4] = (__bf16)f1.x; u.b[5] = (__bf16)f1.y;
        u.b[6] = (__bf16)f1.z; u.b[7] = (__bf16)f1.w;
        *(int4*)(wsB + ((size_t)gw * 64 + lane) * 8) = u.v;
    }
}

// stage one round (2 texts = 16 KB) via global_load_lds, 4 x 1KB per wave
__device__ inline void stage_round(const __bf16* __restrict__ gsrc,
                                   __bf16* dst, int wave, int lane)
{
    #pragma unroll
    for (int q = 0; q < 4; ++q) {
        int seg = wave * 4 + q;
        const __bf16* g = gsrc + (size_t)seg * 512 + lane * 8;
        __bf16*       l = dst  + (size_t)seg * 512 + lane * 8;
        __builtin_amdgcn_global_load_lds(
            (const __attribute__((address_space(1))) void*)g,
            (__attribute__((address_space(3)))       void*)l, 16, 0, 0);
    }
}

// ---------- main kernel ----------
// Block: 4 waves = 2 images x 2 m-halves. Grid: 2048 = 128 pairs x 16 chunks.
// LDS 36 KB -> 4 blocks/CU (16 waves). Per text/wave: 8 ds_read_b128 + 8 MFMA.
__global__ __launch_bounds__(256, 4)
void clip_match_kernel(const __bf16* __restrict__ wsA,
                       const __bf16* __restrict__ wsB,
                       const int* __restrict__ tlen,
                       const float* __restrict__ nlt,
                       float* __restrict__ out)
{
    const int tid  = threadIdx.x;
    const int wave = tid >> 6, lane = tid & 63;
    const int ml   = lane & 31, h = lane >> 5;
    const int tb   = blockIdx.x & 15;    // text chunk (16 texts)
    const int ip   = blockIdx.x >> 4;    // image pair 0..127
    const int ii   = wave & 1;           // image within pair
    const int mh   = wave >> 1;          // m-half (rows mh*32..mh*32+31)
    const int img_i = ip * 2 + ii;

    const float scale = expf(nlt[0]);

    __shared__ __align__(16) __bf16 buf[2][2 * 4096];     // 2 x 16 KB (2 texts)
    __shared__ __align__(16) float  colmax[2][CH][32];    // 4 KB

    // A fragments: 8 x dwordx4, already fragment-linear, no cvt
    bf16x8 afrag[8];
    {
        const __bf16* pa = wsA + (((size_t)img_i * 2 + mh) * 8) * 512;
        #pragma unroll
        for (int ks = 0; ks < 8; ++ks)
            afrag[ks] = *(const bf16x8*)(pa + (size_t)(ks * 64 + lane) * 8);
    }

    // init colmax (1024 floats)
    {
        float4 ninf4 = make_float4(NEG_INF, NEG_INF, NEG_INF, NEG_INF);
        *(float4*)(&colmax[0][0][0] + tid * 4) = ninf4;
    }

    const __bf16* csrc = wsB + (size_t)tb * CH * 4096;   // chunk base

    stage_round(csrc, buf[0], wave, lane);               // texts 0,1
    __syncthreads();

    int c = 0;
    #pragma unroll 1
    for (int r = 0; r < 8; ++r) {
        if (r < 7)
            stage_round(csrc + (size_t)(r + 1) * 2 * 4096, buf[c ^ 1], wave, lane);

        const __bf16* bsrc = buf[c];
        #pragma unroll
        for (int ts = 0; ts < 2; ++ts) {
            const int t = r * 2 + ts;
            bf16x8 bfrag[8];
            #pragma unroll
            for (int ks = 0; ks < 8; ++ks)
                bfrag[ks] = *(const bf16x8*)(bsrc + ts * 4096
                                             + (size_t)(ks * 64 + lane) * 8);
            f32x16 acc = (f32x16)(0.f);
            #pragma unroll
            for (int ks = 0; ks < 8; ++ks)
                acc = __builtin_amdgcn_mfma_f32_32x32x16_bf16(
                    afrag[ks], bfrag[ks], acc, 0, 0, 0);

            // max over this wave's valid rows; C/D: col=lane&31,
            // row r2 = (reg&3)+8*(reg>>2)+4*h, m = mh*32+r2 (valid m<49)
            float cm;
            if (mh == 0) {                 // all 16 regs valid
                float t0[8];
                #pragma unroll
                for (int k = 0; k < 8; ++k) t0[k] = fmaxf(acc[2*k], acc[2*k+1]);
                float t1[4];
                #pragma unroll
                for (int k = 0; k < 4; ++k) t1[k] = fmaxf(t0[2*k], t0[2*k+1]);
                cm = fmaxf(fmaxf(t1[0], t1[1]), fmaxf(t1[2], t1[3]));
            } else {                       // regs 0..7 (+reg8 iff h==0)
                float u0[4];
                #pragma unroll
                for (int k = 0; k < 4; ++k) u0[k] = fmaxf(acc[2*k], acc[2*k+1]);
                cm = fmaxf(fmaxf(u0[0], u0[1]), fmaxf(u0[2], u0[3]));
                float ex = (h == 0) ? acc[8] : NEG_INF;
                cm = fmaxf(cm, ex);
            }
            atomicMax(&colmax[ii][t][ml], cm);   // ds_max, fire-and-forget
        }
        __syncthreads();
        c ^= 1;
    }

    // epilogue: wave w -> image w&1, 8 texts of half w>>1; 4 cols/lane
    {
        const int iw   = wave & 1;
        const int th   = wave >> 1;
        const int t16  = th * 8 + (lane >> 3);
        const int cg   = lane & 7;
        float4 a = *(const float4*)&colmax[iw][t16][cg * 4];
        float s = (a.x + a.y) + (a.z + a.w);
        s += __shfl_xor(s, 1);
        s += __shfl_xor(s, 2);
        s += __shfl_xor(s, 4);           // sum over 32 cols
        if (cg == 0) {
            int tg = tb * CH + t16;
            int ig = ip * 2 + iw;
            float v = s * scale / (float)tlen[tg];
            out[ig * NT + tg] = v;              // logits_per_image[i,t]
            out[NI * NT + tg * NI + ig] = v;    // logits_per_text[t,i]
        }
    }
}

extern "C" void kernel_launch(void* const* d_in, const int* in_sizes, int n_in,
                              void* d_out, int out_size, void* d_ws, size_t ws_size,
                              hipStream_t stream)
{
    const float* img  = (const float*)d_in[0];
    const float* txt  = (const float*)d_in[1];
    const int*   tlen = (const int*)d_in[2];
    const float* nlt  = (const float*)d_in[3];
    float* out = (float*)d_out;

    __bf16* wsA = (__bf16*)d_ws;                 // 4 MB
    __bf16* wsB = wsA + (size_t)4096 * 512;      // 2 MB

    prep_kernel<<<dim3(1536), dim3(256), 0, stream>>>(img, txt, wsA, wsB);
    clip_match_kernel<<<dim3(2048), dim3(256), 0, stream>>>(wsA, wsB, tlen, nlt, out);
}